// Round 1
// baseline (7890.914 us; speedup 1.0000x reference)
//
#include <hip/hip_runtime.h>

// ---------------------------------------------------------------------------
// Hetero-SAGE baseline (fp32, vector ALU).
//   h_t = x_t @ W_t.T + b_t                  (3 projection GEMMs, K=1280/768)
//   per dest d: out_d = h_d @ (sum_r Wr_r).T + (sum_r bl_r)   (1 biased GEMM)
//               for each relation r into d:
//                   sum/cnt scatter-add over edges (atomics)
//                   mean = sum / max(cnt,1)
//                   out_d += mean @ Wl_r.T                    (acc GEMM, K=256)
// ---------------------------------------------------------------------------

#define BM 64
#define BN 64
#define BK 16
#define LDSS 68   // LDS row stride (floats): mult-of-4 (16B align) + 2-way-max banks

template <bool ACC, bool BIAS>
__global__ __launch_bounds__(256) void gemm_tn(
    const float* __restrict__ A,   // [M, K] row-major
    const float* __restrict__ W,   // [256, K] row-major (output col c = row c)
    const float* __restrict__ bias,// [256] or null
    float* __restrict__ C,         // [M, 256]
    int M, int K)
{
    __shared__ float As[BK * LDSS];
    __shared__ float Ws[BK * LDSS];

    const int tid  = threadIdx.x;
    const int tx   = tid & 15;        // col group 0..15
    const int ty   = tid >> 4;        // row group 0..15
    const int row0 = blockIdx.y * BM;
    const int col0 = blockIdx.x * BN;

    const int lr = tid >> 2;          // 0..63 tile row
    const int lk = (tid & 3) << 2;    // 0,4,8,12 k offset

    float acc[4][4] = {};

    const bool arow_ok = (row0 + lr) < M;
    const float* Aload = A + (long)(row0 + lr) * K + lk;
    const float* Wload = W + (long)(col0 + lr) * K + lk;

    for (int k0 = 0; k0 < K; k0 += BK) {
        float4 av = make_float4(0.f, 0.f, 0.f, 0.f);
        if (arow_ok) av = *(const float4*)(Aload + k0);
        const float4 wv = *(const float4*)(Wload + k0);

        As[(lk + 0) * LDSS + lr] = av.x;
        As[(lk + 1) * LDSS + lr] = av.y;
        As[(lk + 2) * LDSS + lr] = av.z;
        As[(lk + 3) * LDSS + lr] = av.w;
        Ws[(lk + 0) * LDSS + lr] = wv.x;
        Ws[(lk + 1) * LDSS + lr] = wv.y;
        Ws[(lk + 2) * LDSS + lr] = wv.z;
        Ws[(lk + 3) * LDSS + lr] = wv.w;
        __syncthreads();

#pragma unroll
        for (int k = 0; k < BK; ++k) {
            const float4 a = *(const float4*)&As[k * LDSS + (ty << 2)];
            const float4 b = *(const float4*)&Ws[k * LDSS + (tx << 2)];
            const float ar[4] = {a.x, a.y, a.z, a.w};
            const float br[4] = {b.x, b.y, b.z, b.w};
#pragma unroll
            for (int i = 0; i < 4; ++i)
#pragma unroll
                for (int j = 0; j < 4; ++j)
                    acc[i][j] = fmaf(ar[i], br[j], acc[i][j]);
        }
        __syncthreads();
    }

#pragma unroll
    for (int i = 0; i < 4; ++i) {
        const int row = row0 + (ty << 2) + i;
        if (row < M) {
            float* cp = C + (long)row * 256 + col0 + (tx << 2);
            float4 v = make_float4(acc[i][0], acc[i][1], acc[i][2], acc[i][3]);
            if (BIAS) {
                const float4 bv = *(const float4*)&bias[col0 + (tx << 2)];
                v.x += bv.x; v.y += bv.y; v.z += bv.z; v.w += bv.w;
            }
            if (ACC) {
                const float4 o = *(const float4*)cp;
                v.x += o.x; v.y += o.y; v.z += o.z; v.w += o.w;
            }
            *(float4*)cp = v;
        }
    }
}

// 64 threads per edge, 4 floats each (256-wide features)
__global__ void scatter_kernel(const float* __restrict__ h,
                               const int* __restrict__ ei, int E,
                               float* __restrict__ sum, float* __restrict__ cnt)
{
    const long gid = (long)blockIdx.x * blockDim.x + threadIdx.x;
    const long e = gid >> 6;
    if (e >= E) return;
    const int c = (int)(gid & 63) << 2;
    const int src = ei[e];
    const int dst = ei[E + e];
    const float4 v = *(const float4*)&h[(long)src * 256 + c];
    float* s = sum + (long)dst * 256 + c;
    atomicAdd(s + 0, v.x);
    atomicAdd(s + 1, v.y);
    atomicAdd(s + 2, v.z);
    atomicAdd(s + 3, v.w);
    if (c == 0) atomicAdd(cnt + dst, 1.0f);
}

__global__ void normalize_kernel(float* __restrict__ sum,
                                 const float* __restrict__ cnt, long n)
{
    const long i = (long)blockIdx.x * blockDim.x + threadIdx.x;  // float4 index
    if (i >= n * 64) return;
    const long row = i >> 6;
    const float c = fmaxf(cnt[row], 1.0f);
    float4 v = ((float4*)sum)[i];
    v.x /= c; v.y /= c; v.z /= c; v.w /= c;
    ((float4*)sum)[i] = v;
}

__global__ void combine_kernel(const float* __restrict__ Wr,
                               const float* __restrict__ bl,
                               int r0, int r1, int r2, int nr,
                               float* __restrict__ Wc, float* __restrict__ bc)
{
    const int i = blockIdx.x * blockDim.x + threadIdx.x;
    if (i < 256 * 256) {
        float s = Wr[r0 * 65536 + i];
        if (nr > 1) s += Wr[r1 * 65536 + i];
        if (nr > 2) s += Wr[r2 * 65536 + i];
        Wc[i] = s;
    }
    if (i < 256) {
        float s = bl[r0 * 256 + i];
        if (nr > 1) s += bl[r1 * 256 + i];
        if (nr > 2) s += bl[r2 * 256 + i];
        bc[i] = s;
    }
}

extern "C" void kernel_launch(void* const* d_in, const int* in_sizes, int n_in,
                              void* d_out, int out_size, void* d_ws, size_t ws_size,
                              hipStream_t stream)
{
    const float* x_conv = (const float*)d_in[0];
    const float* x_sent = (const float*)d_in[1];
    const float* x_word = (const float*)d_in[2];
    const int* ei_cs = (const int*)d_in[3];
    const int* ei_ss = (const int*)d_in[4];
    const int* ei_sw = (const int*)d_in[5];
    const int* ei_ww = (const int*)d_in[6];
    const int* ei_sc = (const int*)d_in[7];
    const int* ei_ws = (const int*)d_in[8];
    const float* W_conv = (const float*)d_in[9];
    const float* b_conv = (const float*)d_in[10];
    const float* W_sent = (const float*)d_in[11];
    const float* b_sent = (const float*)d_in[12];
    const float* W_word = (const float*)d_in[13];
    const float* b_word = (const float*)d_in[14];
    const float* Wl = (const float*)d_in[15];
    const float* bl = (const float*)d_in[16];
    const float* Wr = (const float*)d_in[17];

    const int E_cs = in_sizes[3] / 2;
    const int E_ss = in_sizes[4] / 2;
    const int E_sw = in_sizes[5] / 2;
    const int E_ww = in_sizes[6] / 2;
    const int E_sc = in_sizes[7] / 2;
    const int E_ws = in_sizes[8] / 2;

    const int NC = 2000, NS = 50000, NW = 100000;

    float* ws = (float*)d_ws;
    float* hc  = ws;                       // 2000*256      =    512000
    float* hs  = hc  + (long)NC * 256;     // 50000*256     =  12800000
    float* hw  = hs  + (long)NS * 256;     // 100000*256    =  25600000
    float* sum = hw  + (long)NW * 256;     // scratch (max) =  25600000
    float* cnt = sum + (long)NW * 256;     //                   100000
    float* Wc  = cnt + NW;                 //                    65536
    float* bc  = Wc  + 65536;              //                      256

    float* out_conv = (float*)d_out;
    float* out_sent = out_conv + (long)NC * 256;
    float* out_word = out_sent + (long)NS * 256;

    auto ggrid = [](int M) { return dim3(4, (M + BM - 1) / BM); };

    // --- projections ---
    gemm_tn<false, true><<<ggrid(NC), 256, 0, stream>>>(x_conv, W_conv, b_conv, hc, NC, 1280);
    gemm_tn<false, true><<<ggrid(NS), 256, 0, stream>>>(x_sent, W_sent, b_sent, hs, NS, 1280);
    gemm_tn<false, true><<<ggrid(NW), 256, 0, stream>>>(x_word, W_word, b_word, hw, NW, 768);

    auto do_dest = [&](float* out, const float* hdst, int n_dst,
                       int r0, int r1, int r2, int nr) {
        combine_kernel<<<256, 256, 0, stream>>>(Wr, bl, r0, r1, r2, nr, Wc, bc);
        gemm_tn<false, true><<<ggrid(n_dst), 256, 0, stream>>>(hdst, Wc, bc, out, n_dst, 256);
    };
    auto do_rel = [&](float* out, const float* hsrc, const int* ei, int E,
                      int n_dst, int r) {
        hipMemsetAsync(sum, 0, (size_t)n_dst * 256 * sizeof(float), stream);
        hipMemsetAsync(cnt, 0, (size_t)n_dst * sizeof(float), stream);
        const long tot = (long)E * 64;
        scatter_kernel<<<(int)((tot + 255) / 256), 256, 0, stream>>>(hsrc, ei, E, sum, cnt);
        const long ng = (long)n_dst * 64;
        normalize_kernel<<<(int)((ng + 255) / 256), 256, 0, stream>>>(sum, cnt, n_dst);
        gemm_tn<true, false><<<ggrid(n_dst), 256, 0, stream>>>(
            sum, Wl + (long)r * 65536, nullptr, out, n_dst, 256);
    };

    // conversation dest: relation 4 = sc (src: sentences)
    do_dest(out_conv, hc, NC, 4, 0, 0, 1);
    do_rel(out_conv, hs, ei_sc, E_sc, NC, 4);

    // sentence dest: relations 0 = cs (hc), 1 = ss (hs), 5 = ws (hw)
    do_dest(out_sent, hs, NS, 0, 1, 5, 3);
    do_rel(out_sent, hc, ei_cs, E_cs, NS, 0);
    do_rel(out_sent, hs, ei_ss, E_ss, NS, 1);
    do_rel(out_sent, hw, ei_ws, E_ws, NS, 5);

    // word dest: relations 2 = sw (hs), 3 = ww (hw)
    do_dest(out_word, hw, NW, 2, 3, 0, 2);
    do_rel(out_word, hs, ei_sw, E_sw, NW, 2);
    do_rel(out_word, hw, ei_ww, E_ww, NW, 3);
}

// Round 2
// 3026.262 us; speedup vs baseline: 2.6075x; 2.6075x over previous
//
#include <hip/hip_runtime.h>

// ---------------------------------------------------------------------------
// Hetero-SAGE, round 2: atomic scatter -> CSR-build + per-wave gather.
//   h_t = x_t @ W_t.T + b_t                         (3 projection GEMMs)
//   per dest d: out_d = h_d @ (sum_r Wr_r).T + (sum_r bl_r)
//               per relation r into d:
//                 count -> scan -> fill (CSR by dst)
//                 gather: 1 wave per dst row, mean in registers, 1 write
//                 out_d += mean @ Wl_r.T            (acc GEMM, K=256)
// ---------------------------------------------------------------------------

#define BM 64
#define BN 64
#define BK 16
#define LDSS 68   // LDS row stride (floats): 16B-aligned, <=2-way bank aliasing

template <bool ACC, bool BIAS>
__global__ __launch_bounds__(256) void gemm_tn(
    const float* __restrict__ A,   // [M, K] row-major
    const float* __restrict__ W,   // [256, K] row-major (output col c = row c)
    const float* __restrict__ bias,// [256] or null
    float* __restrict__ C,         // [M, 256]
    int M, int K)
{
    __shared__ float As[BK * LDSS];
    __shared__ float Ws[BK * LDSS];

    const int tid  = threadIdx.x;
    const int tx   = tid & 15;
    const int ty   = tid >> 4;
    const int row0 = blockIdx.y * BM;
    const int col0 = blockIdx.x * BN;

    const int lr = tid >> 2;          // 0..63 tile row
    const int lk = (tid & 3) << 2;    // 0,4,8,12 k offset

    float acc[4][4] = {};

    const bool arow_ok = (row0 + lr) < M;
    const float* Aload = A + (long)(row0 + lr) * K + lk;
    const float* Wload = W + (long)(col0 + lr) * K + lk;

    for (int k0 = 0; k0 < K; k0 += BK) {
        float4 av = make_float4(0.f, 0.f, 0.f, 0.f);
        if (arow_ok) av = *(const float4*)(Aload + k0);
        const float4 wv = *(const float4*)(Wload + k0);

        As[(lk + 0) * LDSS + lr] = av.x;
        As[(lk + 1) * LDSS + lr] = av.y;
        As[(lk + 2) * LDSS + lr] = av.z;
        As[(lk + 3) * LDSS + lr] = av.w;
        Ws[(lk + 0) * LDSS + lr] = wv.x;
        Ws[(lk + 1) * LDSS + lr] = wv.y;
        Ws[(lk + 2) * LDSS + lr] = wv.z;
        Ws[(lk + 3) * LDSS + lr] = wv.w;
        __syncthreads();

#pragma unroll
        for (int k = 0; k < BK; ++k) {
            const float4 a = *(const float4*)&As[k * LDSS + (ty << 2)];
            const float4 b = *(const float4*)&Ws[k * LDSS + (tx << 2)];
            const float ar[4] = {a.x, a.y, a.z, a.w};
            const float br[4] = {b.x, b.y, b.z, b.w};
#pragma unroll
            for (int i = 0; i < 4; ++i)
#pragma unroll
                for (int j = 0; j < 4; ++j)
                    acc[i][j] = fmaf(ar[i], br[j], acc[i][j]);
        }
        __syncthreads();
    }

#pragma unroll
    for (int i = 0; i < 4; ++i) {
        const int row = row0 + (ty << 2) + i;
        if (row < M) {
            float* cp = C + (long)row * 256 + col0 + (tx << 2);
            float4 v = make_float4(acc[i][0], acc[i][1], acc[i][2], acc[i][3]);
            if (BIAS) {
                const float4 bv = *(const float4*)&bias[col0 + (tx << 2)];
                v.x += bv.x; v.y += bv.y; v.z += bv.z; v.w += bv.w;
            }
            if (ACC) {
                const float4 o = *(const float4*)cp;
                v.x += o.x; v.y += o.y; v.z += o.z; v.w += o.w;
            }
            *(float4*)cp = v;
        }
    }
}

// ------------------------------- CSR build ---------------------------------

__device__ inline int wave_incl_scan(int x, int lane)
{
#pragma unroll
    for (int off = 1; off < 64; off <<= 1) {
        int t = __shfl_up(x, off);
        if (lane >= off) x += t;
    }
    return x;
}

__global__ void count_deg(const int* __restrict__ ei, int E, int* __restrict__ cnt)
{
    int e = blockIdx.x * 256 + threadIdx.x;
    if (e < E) atomicAdd(&cnt[ei[E + e]], 1);
}

// per-1024-block exclusive scan; writes within-block exclusive to rowptr,
// block total to bsum
__global__ __launch_bounds__(1024) void scan_block(
    const int* __restrict__ cnt, int* __restrict__ rowptr,
    int* __restrict__ bsum, int n)
{
    __shared__ int wsum[16];
    const int tid = threadIdx.x, lane = tid & 63, w = tid >> 6;
    const int i = blockIdx.x * 1024 + tid;
    const int v = (i < n) ? cnt[i] : 0;
    int x = wave_incl_scan(v, lane);
    if (lane == 63) wsum[w] = x;
    __syncthreads();
    if (w == 0) {
        int s = (lane < 16) ? wsum[lane] : 0;
        s = wave_incl_scan(s, lane);
        if (lane < 16) wsum[lane] = s;
    }
    __syncthreads();
    const int base = w ? wsum[w - 1] : 0;
    if (i < n) rowptr[i] = base + x - v;
    if (tid == 1023) bsum[blockIdx.x] = base + x;
}

// single-wave scan of block sums (nb <= ~100); writes grand total to *total_out
__global__ void scan_tops(int* __restrict__ bsum, int nb, int* __restrict__ total_out)
{
    const int lane = threadIdx.x;
    int carry = 0;
    for (int b = 0; b < nb; b += 64) {
        const int i = b + lane;
        const int v = (i < nb) ? bsum[i] : 0;
        const int x = wave_incl_scan(v, lane);
        if (i < nb) bsum[i] = carry + x - v;
        carry += __shfl(x, 63);
    }
    if (lane == 0) *total_out = carry;
}

__global__ void scan_apply(int* __restrict__ rowptr, const int* __restrict__ bsum,
                           int* __restrict__ cursor, int n)
{
    const int i = blockIdx.x * 256 + threadIdx.x;
    if (i < n) {
        const int v = rowptr[i] + bsum[i >> 10];
        rowptr[i] = v;
        cursor[i] = v;
    }
}

__global__ void fill_csr(const int* __restrict__ ei, int E,
                         int* __restrict__ cursor, int* __restrict__ esrc)
{
    const int e = blockIdx.x * 256 + threadIdx.x;
    if (e < E) {
        const int src = ei[e];
        const int dst = ei[E + e];
        const int pos = atomicAdd(&cursor[dst], 1);
        esrc[pos] = src;
    }
}

// one wave per destination row: 64 lanes x float4 = 256 features
__global__ __launch_bounds__(256) void gather_mean(
    const float* __restrict__ h, const int* __restrict__ rowptr,
    const int* __restrict__ esrc, float* __restrict__ mean, int n_dst)
{
    const int gid = blockIdx.x * 256 + threadIdx.x;
    const int d = gid >> 6;
    if (d >= n_dst) return;
    const int lane = threadIdx.x & 63;
    const int beg = rowptr[d], end = rowptr[d + 1];
    float4 acc = make_float4(0.f, 0.f, 0.f, 0.f);
    const float* hp = h + (size_t)(lane << 2);
    for (int e = beg; e < end; ++e) {
        const int s = esrc[e];
        const float4 v = *(const float4*)(hp + (size_t)s * 256);
        acc.x += v.x; acc.y += v.y; acc.z += v.z; acc.w += v.w;
    }
    const float inv = (end > beg) ? 1.0f / (float)(end - beg) : 0.0f;
    float4 o = make_float4(acc.x * inv, acc.y * inv, acc.z * inv, acc.w * inv);
    *(float4*)(mean + (size_t)d * 256 + (lane << 2)) = o;
}

__global__ void combine_kernel(const float* __restrict__ Wr,
                               const float* __restrict__ bl,
                               int r0, int r1, int r2, int nr,
                               float* __restrict__ Wc, float* __restrict__ bc)
{
    const int i = blockIdx.x * blockDim.x + threadIdx.x;
    if (i < 256 * 256) {
        float s = Wr[r0 * 65536 + i];
        if (nr > 1) s += Wr[r1 * 65536 + i];
        if (nr > 2) s += Wr[r2 * 65536 + i];
        Wc[i] = s;
    }
    if (i < 256) {
        float s = bl[r0 * 256 + i];
        if (nr > 1) s += bl[r1 * 256 + i];
        if (nr > 2) s += bl[r2 * 256 + i];
        bc[i] = s;
    }
}

extern "C" void kernel_launch(void* const* d_in, const int* in_sizes, int n_in,
                              void* d_out, int out_size, void* d_ws, size_t ws_size,
                              hipStream_t stream)
{
    const float* x_conv = (const float*)d_in[0];
    const float* x_sent = (const float*)d_in[1];
    const float* x_word = (const float*)d_in[2];
    const int* ei_cs = (const int*)d_in[3];
    const int* ei_ss = (const int*)d_in[4];
    const int* ei_sw = (const int*)d_in[5];
    const int* ei_ww = (const int*)d_in[6];
    const int* ei_sc = (const int*)d_in[7];
    const int* ei_ws = (const int*)d_in[8];
    const float* W_conv = (const float*)d_in[9];
    const float* b_conv = (const float*)d_in[10];
    const float* W_sent = (const float*)d_in[11];
    const float* b_sent = (const float*)d_in[12];
    const float* W_word = (const float*)d_in[13];
    const float* b_word = (const float*)d_in[14];
    const float* Wl = (const float*)d_in[15];
    const float* bl = (const float*)d_in[16];
    const float* Wr = (const float*)d_in[17];

    const int E_cs = in_sizes[3] / 2;
    const int E_ss = in_sizes[4] / 2;
    const int E_sw = in_sizes[5] / 2;
    const int E_ww = in_sizes[6] / 2;
    const int E_sc = in_sizes[7] / 2;
    const int E_ws = in_sizes[8] / 2;

    const int NC = 2000, NS = 50000, NW = 100000;

    float* ws = (float*)d_ws;
    float* hc   = ws;                        //   512000
    float* hs   = hc + (long)NC * 256;       // 12800000
    float* hw   = hs + (long)NS * 256;       // 25600000
    float* mean = hw + (long)NW * 256;       // 25600000 (max NW rows)
    int*  cntcur = (int*)(mean + (long)NW * 256); // NW ints (cnt, then cursor)
    float* Wc   = (float*)(cntcur + NW);     // 65536
    float* bc   = Wc + 65536;                // 256
    int*  rowptr = (int*)(bc + 256);         // NW+1 (pad to 100032)
    int*  bsum   = rowptr + 100032;          // 128
    int*  esrc   = bsum + 128;               // max E = 400000

    float* out_conv = (float*)d_out;
    float* out_sent = out_conv + (long)NC * 256;
    float* out_word = out_sent + (long)NS * 256;

    auto ggrid = [](int M) { return dim3(4, (M + BM - 1) / BM); };

    // --- projections ---
    gemm_tn<false, true><<<ggrid(NC), 256, 0, stream>>>(x_conv, W_conv, b_conv, hc, NC, 1280);
    gemm_tn<false, true><<<ggrid(NS), 256, 0, stream>>>(x_sent, W_sent, b_sent, hs, NS, 1280);
    gemm_tn<false, true><<<ggrid(NW), 256, 0, stream>>>(x_word, W_word, b_word, hw, NW, 768);

    auto do_dest = [&](float* out, const float* hdst, int n_dst,
                       int r0, int r1, int r2, int nr) {
        combine_kernel<<<256, 256, 0, stream>>>(Wr, bl, r0, r1, r2, nr, Wc, bc);
        gemm_tn<false, true><<<ggrid(n_dst), 256, 0, stream>>>(hdst, Wc, bc, out, n_dst, 256);
    };
    auto do_rel = [&](float* out, const float* hsrc, const int* ei, int E,
                      int n_dst, int r) {
        hipMemsetAsync(cntcur, 0, (size_t)n_dst * sizeof(int), stream);
        count_deg<<<(E + 255) / 256, 256, 0, stream>>>(ei, E, cntcur);
        const int nb = (n_dst + 1023) / 1024;
        scan_block<<<nb, 1024, 0, stream>>>(cntcur, rowptr, bsum, n_dst);
        scan_tops<<<1, 64, 0, stream>>>(bsum, nb, rowptr + n_dst);
        scan_apply<<<(n_dst + 255) / 256, 256, 0, stream>>>(rowptr, bsum, cntcur, n_dst);
        fill_csr<<<(E + 255) / 256, 256, 0, stream>>>(ei, E, cntcur, esrc);
        gather_mean<<<(n_dst + 3) / 4, 256, 0, stream>>>(hsrc, rowptr, esrc, mean, n_dst);
        gemm_tn<true, false><<<ggrid(n_dst), 256, 0, stream>>>(
            mean, Wl + (long)r * 65536, nullptr, out, n_dst, 256);
    };

    // conversation dest: relation 4 = sc (src: sentences)
    do_dest(out_conv, hc, NC, 4, 0, 0, 1);
    do_rel(out_conv, hs, ei_sc, E_sc, NC, 4);

    // sentence dest: relations 0 = cs (hc), 1 = ss (hs), 5 = ws (hw)
    do_dest(out_sent, hs, NS, 0, 1, 5, 3);
    do_rel(out_sent, hc, ei_cs, E_cs, NS, 0);
    do_rel(out_sent, hs, ei_ss, E_ss, NS, 1);
    do_rel(out_sent, hw, ei_ws, E_ws, NS, 5);

    // word dest: relations 2 = sw (hs), 3 = ww (hw)
    do_dest(out_word, hw, NW, 2, 3, 0, 2);
    do_rel(out_word, hs, ei_sw, E_sw, NW, 2);
    do_rel(out_word, hw, ei_ww, E_ww, NW, 3);
}